// Round 10
// baseline (520.753 us; speedup 1.0000x reference)
//
#include <hip/hip_runtime.h>
#include <math.h>

#define NN 100000
#define NE 1000000
#define NG 100
#define NL 3
#define NEG 0.2f

__device__ __forceinline__ float lrelu(float x){ return fmaxf(x, NEG*x); }

// Ve2[(l*4+h)*64 + d] = sum_c We[l][d][h*16+c] * ae[l][h*16+c]  (d-contiguous)
__global__ void k_ve(const float* __restrict__ We, const float* __restrict__ ae,
                     float* __restrict__ Ve2){
  int i = blockIdx.x*blockDim.x + threadIdx.x;
  if(i >= NL*4*64) return;
  int d = i & 63, h = (i>>6)&3, l = i>>8;
  const float* w = We + l*4096 + d*64 + h*16;
  const float* a = ae + l*64 + h*16;
  float s = 0.f;
  #pragma unroll
  for(int c=0;c<16;c++) s = fmaf(w[c], a[c], s);
  Ve2[(l*4+h)*64 + d] = s;
}

// h0 = relu([x, femb[ft]] @ nodeW + b) ; thread per (n,d)
__global__ void k_h0(const float* __restrict__ x, const int* __restrict__ ft,
                     const float* __restrict__ femb, const float* __restrict__ W,
                     const float* __restrict__ b, float* __restrict__ h){
  int i = blockIdx.x*blockDim.x + threadIdx.x;
  if(i >= NN*64) return;
  int n = i>>6, d = i&63;
  const float* xr = x + (size_t)n*9;
  const float* fe = femb + ft[n]*8;
  float s = b[d];
  #pragma unroll
  for(int k=0;k<9;k++) s = fmaf(xr[k], W[k*64+d], s);
  #pragma unroll
  for(int j=0;j<8;j++) s = fmaf(fe[j], W[(9+j)*64+d], s);
  h[i] = fmaxf(s, 0.f);
}

// 4 edges/thread (strided chunks): 4 independent atomic chains in flight
__global__ void k_deg(const int* __restrict__ dst, int* __restrict__ deg){
  int i = blockIdx.x*blockDim.x + threadIdx.x;
  if(i >= NE/4) return;
  #pragma unroll
  for(int k=0;k<4;k++){
    int e = i + k*(NE/4);
    atomicAdd(&deg[dst[e]], 1);
  }
}

// exclusive scan of deg -> rowptr (hierarchical, 1024 elems/block)
__global__ void k_scan1(const int* __restrict__ deg, int* __restrict__ rp,
                        int* __restrict__ bsum){
  __shared__ int sd[256];
  int t = threadIdx.x;
  int base = blockIdx.x*1024 + t*4;
  int v0 = (base+0<NN)?deg[base+0]:0;
  int v1 = (base+1<NN)?deg[base+1]:0;
  int v2 = (base+2<NN)?deg[base+2]:0;
  int v3 = (base+3<NN)?deg[base+3]:0;
  int ts = v0+v1+v2+v3;
  sd[t] = ts; __syncthreads();
  for(int off=1; off<256; off<<=1){
    int add = (t>=off)? sd[t-off] : 0;
    __syncthreads();
    sd[t] += add;
    __syncthreads();
  }
  int excl = sd[t] - ts;
  if(t==255) bsum[blockIdx.x] = sd[t];
  if(base+0<NN) rp[base+0]=excl;
  if(base+1<NN) rp[base+1]=excl+v0;
  if(base+2<NN) rp[base+2]=excl+v0+v1;
  if(base+3<NN) rp[base+3]=excl+v0+v1+v2;
}
__global__ void k_scan2(int* __restrict__ bsum, int nb){
  if(threadIdx.x==0 && blockIdx.x==0){
    int acc=0;
    for(int i=0;i<nb;i++){ int v=bsum[i]; bsum[i]=acc; acc+=v; }
  }
}
__global__ void k_scan3(int* __restrict__ rp, const int* __restrict__ bsum){
  int i = blockIdx.x*blockDim.x + threadIdx.x;
  if(i < NN) rp[i] += bsum[i>>10];
  if(i == 0) rp[NN] = NE;
}

// fused: edge_h = relu(eattr@eW+b); al[l][h] = edge_h . Ve2[l][h][:]
// inline CSR scatter (R5 config): csrc (4B) + 3 per-layer cal streams (16B)
__global__ void k_edge(const float* __restrict__ eattr, const int* __restrict__ src,
                       const int* __restrict__ dst, const float* __restrict__ eW,
                       const float* __restrict__ eb, const float* __restrict__ Ve2,
                       const int* __restrict__ rp, int* __restrict__ fill,
                       int* __restrict__ csrc, float* __restrict__ cal){
  int e = blockIdx.x*blockDim.x + threadIdx.x;
  if(e >= NE) return;
  float a0 = eattr[(size_t)e*2], a1 = eattr[(size_t)e*2+1];
  float acc[12];
  #pragma unroll
  for(int t=0;t<12;t++) acc[t]=0.f;
  #pragma unroll 4
  for(int d=0; d<64; d+=4){
    float4 w0 = *(const float4*)&eW[d];
    float4 w1 = *(const float4*)&eW[64+d];
    float4 bb = *(const float4*)&eb[d];
    float4 eh;
    eh.x = fmaxf(fmaf(a0, w0.x, fmaf(a1, w1.x, bb.x)), 0.f);
    eh.y = fmaxf(fmaf(a0, w0.y, fmaf(a1, w1.y, bb.y)), 0.f);
    eh.z = fmaxf(fmaf(a0, w0.z, fmaf(a1, w1.z, bb.z)), 0.f);
    eh.w = fmaxf(fmaf(a0, w0.w, fmaf(a1, w1.w, bb.w)), 0.f);
    #pragma unroll
    for(int j=0;j<12;j++){
      float4 v = *(const float4*)&Ve2[j*64 + d];
      acc[j] = fmaf(eh.x, v.x, acc[j]);
      acc[j] = fmaf(eh.y, v.y, acc[j]);
      acc[j] = fmaf(eh.z, v.z, acc[j]);
      acc[j] = fmaf(eh.w, v.w, acc[j]);
    }
  }
  int dd = dst[e];
  int pos = rp[dd] + atomicAdd(&fill[dd], 1);
  csrc[pos] = src[e];
  *(float4*)&cal[(size_t)pos*4]          = make_float4(acc[0], acc[1], acc[2],  acc[3]);
  *(float4*)&cal[((size_t)NE   + pos)*4] = make_float4(acc[4], acc[5], acc[6],  acc[7]);
  *(float4*)&cal[((size_t)NE*2 + pos)*4] = make_float4(acc[8], acc[9], acc[10], acc[11]);
}

// xh = h@W as LDS-tiled GEMM: 64-node tile, 256 threads, 4x4 micro-tile/thread.
// Epilogue fuses alsd[n][h] = sum_d xh*aS , sum_d xh*aD via 4-lane shfl reduce.
__global__ __launch_bounds__(256) void k_xh(
    const float* __restrict__ hin, const float* __restrict__ W,
    const float* __restrict__ aS, const float* __restrict__ aD,
    float* __restrict__ xh, float* __restrict__ alsd){
  __shared__ float hs[64][68];
  __shared__ float Ws[64][64];
  int t  = threadIdx.x;
  int td = t & 15;
  int tn = t >> 4;
  int n0 = blockIdx.x*64;
  size_t base = (size_t)n0*64;
  #pragma unroll
  for(int i=0;i<4;i++){
    int idx4 = t + i*256;
    int row  = idx4 >> 4;
    int c4   = (idx4 & 15)*4;
    float4 hv = make_float4(0.f,0.f,0.f,0.f);
    if(base + (size_t)idx4*4 < (size_t)NN*64)
      hv = *(const float4*)&hin[base + (size_t)idx4*4];
    *(float4*)&hs[row][c4] = hv;
    *(float4*)&Ws[row][c4] = *(const float4*)&W[(size_t)idx4*4];
  }
  __syncthreads();

  float acc[4][4];
  #pragma unroll
  for(int i=0;i<4;i++)
    #pragma unroll
    for(int j=0;j<4;j++) acc[i][j]=0.f;

  for(int k=0;k<64;k+=4){
    float4 w0 = *(float4*)&Ws[k+0][td*4];
    float4 w1 = *(float4*)&Ws[k+1][td*4];
    float4 w2 = *(float4*)&Ws[k+2][td*4];
    float4 w3 = *(float4*)&Ws[k+3][td*4];
    #pragma unroll
    for(int i=0;i<4;i++){
      float4 hv = *(float4*)&hs[tn*4+i][k];
      acc[i][0] = fmaf(hv.x, w0.x, acc[i][0]);
      acc[i][1] = fmaf(hv.x, w0.y, acc[i][1]);
      acc[i][2] = fmaf(hv.x, w0.z, acc[i][2]);
      acc[i][3] = fmaf(hv.x, w0.w, acc[i][3]);
      acc[i][0] = fmaf(hv.y, w1.x, acc[i][0]);
      acc[i][1] = fmaf(hv.y, w1.y, acc[i][1]);
      acc[i][2] = fmaf(hv.y, w1.z, acc[i][2]);
      acc[i][3] = fmaf(hv.y, w1.w, acc[i][3]);
      acc[i][0] = fmaf(hv.z, w2.x, acc[i][0]);
      acc[i][1] = fmaf(hv.z, w2.y, acc[i][1]);
      acc[i][2] = fmaf(hv.z, w2.z, acc[i][2]);
      acc[i][3] = fmaf(hv.z, w2.w, acc[i][3]);
      acc[i][0] = fmaf(hv.w, w3.x, acc[i][0]);
      acc[i][1] = fmaf(hv.w, w3.y, acc[i][1]);
      acc[i][2] = fmaf(hv.w, w3.z, acc[i][2]);
      acc[i][3] = fmaf(hv.w, w3.w, acc[i][3]);
    }
  }

  float as0 = aS[td*4+0], as1 = aS[td*4+1], as2 = aS[td*4+2], as3 = aS[td*4+3];
  float ad0 = aD[td*4+0], ad1 = aD[td*4+1], ad2 = aD[td*4+2], ad3 = aD[td*4+3];
  int head = td>>2;

  #pragma unroll
  for(int i=0;i<4;i++){
    int n = n0 + tn*4 + i;
    if(n >= NN) break;
    *(float4*)&xh[(size_t)n*64 + td*4] =
        make_float4(acc[i][0], acc[i][1], acc[i][2], acc[i][3]);
    float vs = acc[i][0]*as0 + acc[i][1]*as1 + acc[i][2]*as2 + acc[i][3]*as3;
    float vd = acc[i][0]*ad0 + acc[i][1]*ad1 + acc[i][2]*ad2 + acc[i][3]*ad3;
    vs += __shfl_xor(vs, 1); vs += __shfl_xor(vs, 2);
    vd += __shfl_xor(vd, 1); vd += __shfl_xor(vd, 2);
    if((td&3)==0){
      alsd[(size_t)n*8 + head]     = vs;
      alsd[(size_t)n*8 + 4 + head] = vd;
    }
  }
}

// per node: TWO waves split the edge range (contiguous halves), each runs
// defer-max online softmax over all 64 dims for its half; exact state merge
// via LDS; wave A adds self-loop and writes. n scalarized via readfirstlane.
__global__ __launch_bounds__(256) void k_gat(
    const float* __restrict__ xh, const float* __restrict__ alsd,
    const int* __restrict__ rp, const int* __restrict__ csrc,
    const float* __restrict__ cal, const float* __restrict__ bias,
    float* __restrict__ hout){
  __shared__ float sm[2][64][4];         // [node slot][lane][{m,den,acc,sum_al}]
  int t = threadIdx.x;
  int wid  = t >> 6;                     // 0..3
  int lane = t & 63;
  int d = lane, h = d >> 4;
  int half = wid & 1;                    // 0 = A, 1 = B
  int slot = wid >> 1;                   // node slot within block
  int n = __builtin_amdgcn_readfirstlane(blockIdx.x*2 + slot);   // NN even
  int r0 = rp[n], r1 = rp[n+1];          // scalar loads
  int dg = r1 - r0;
  int mid = r0 + ((dg + 1) >> 1);
  int pa = half ? mid : r0;
  int pb = half ? r1  : mid;
  float alD_n = alsd[(size_t)n*8 + 4 + h];
  float m = -1e30f, den = 0.f, acc = 0.f, sum_al = 0.f;
  int p = pa;
  for(; p+4 <= pb; p += 4){
    int s0 = csrc[p+0];                  // scalar loads (p scalar)
    int s1 = csrc[p+1];
    int s2 = csrc[p+2];
    int s3 = csrc[p+3];
    float e0 = cal[(size_t)(p+0)*4 + h];
    float e1 = cal[(size_t)(p+1)*4 + h];
    float e2 = cal[(size_t)(p+2)*4 + h];
    float e3 = cal[(size_t)(p+3)*4 + h];
    float a0 = alsd[(size_t)s0*8 + h];
    float a1 = alsd[(size_t)s1*8 + h];
    float a2 = alsd[(size_t)s2*8 + h];
    float a3 = alsd[(size_t)s3*8 + h];
    float x0 = xh[(size_t)s0*64 + d];
    float x1 = xh[(size_t)s1*64 + d];
    float x2 = xh[(size_t)s2*64 + d];
    float x3 = xh[(size_t)s3*64 + d];
    sum_al += e0 + e1 + e2 + e3;
    float l0 = lrelu(a0 + alD_n + e0);
    float l1 = lrelu(a1 + alD_n + e1);
    float l2 = lrelu(a2 + alD_n + e2);
    float l3 = lrelu(a3 + alD_n + e3);
    float pmax = fmaxf(fmaxf(l0, l1), fmaxf(l2, l3));
    if(pmax > m + 8.f){                  // rare; exp(-1e30-x)->0 handles init
      float sc = __expf(m - pmax);
      den *= sc; acc *= sc; m = pmax;
    }
    float w0 = __expf(l0 - m); den += w0; acc = fmaf(w0, x0, acc);
    float w1 = __expf(l1 - m); den += w1; acc = fmaf(w1, x1, acc);
    float w2 = __expf(l2 - m); den += w2; acc = fmaf(w2, x2, acc);
    float w3 = __expf(l3 - m); den += w3; acc = fmaf(w3, x3, acc);
  }
  for(; p < pb; p++){
    int s = csrc[p];
    float e = cal[(size_t)p*4 + h];
    float as = alsd[(size_t)s*8 + h];
    float xv = xh[(size_t)s*64 + d];
    sum_al += e;
    float lg = lrelu(as + alD_n + e);
    if(lg > m + 8.f){
      float sc = __expf(m - lg);
      den *= sc; acc *= sc; m = lg;
    }
    float w = __expf(lg - m); den += w; acc = fmaf(w, xv, acc);
  }
  // merge the two half-states (exact)
  if(half == 1){
    sm[slot][lane][0] = m;
    sm[slot][lane][1] = den;
    sm[slot][lane][2] = acc;
    sm[slot][lane][3] = sum_al;
  }
  __syncthreads();
  if(half == 1) return;
  float m2   = sm[slot][lane][0];
  float den2 = sm[slot][lane][1];
  float acc2 = sm[slot][lane][2];
  sum_al    += sm[slot][lane][3];
  float M  = fmaxf(m, m2);
  float f1 = __expf(m - M);
  float f2 = __expf(m2 - M);
  den = den*f1 + den2*f2;
  acc = acc*f1 + acc2*f2;
  m = M;
  // self-loop (exact merge at reference m)
  float alS_n = alsd[(size_t)n*8 + h];
  float loop_al = dg>0 ? sum_al/(float)dg : 0.f;
  float la = lrelu(alS_n + alD_n + loop_al);
  float nm = fmaxf(m, la);
  float sc = __expf(m - nm);
  float wl = __expf(la - nm);
  den = den*sc + wl;
  acc = fmaf(wl, xh[(size_t)n*64+d], acc*sc);
  hout[(size_t)n*64+d] = fmaxf(acc/den + bias[d], 0.f);
}

// masked scatter-mean pooling: 1 wave per 64-node chunk, batch is sorted
__global__ void k_pool(const float* __restrict__ h, const int* __restrict__ batch,
                       const float* __restrict__ mask, float* __restrict__ hsum,
                       float* __restrict__ cnt){
  int d = threadIdx.x;
  int start = blockIdx.x*64;
  if(start >= NN) return;
  int end = min(start+64, NN);
  int curg = batch[start];
  float acc = 0.f, c = 0.f;
  for(int n=start; n<end; n++){
    int g = batch[n];
    if(g != curg){
      atomicAdd(&hsum[(size_t)curg*64+d], acc);
      if(d==0) atomicAdd(&cnt[curg], c);
      acc = 0.f; c = 0.f; curg = g;
    }
    float mk = mask[n];
    acc = fmaf(h[(size_t)n*64+d], mk, acc);
    if(d==0) c += mk;
  }
  atomicAdd(&hsum[(size_t)curg*64+d], acc);
  if(d==0) atomicAdd(&cnt[curg], c);
}

// hp = hsum/clip(cnt,1); mu = hp@muW+mub ; logvar = hp@lvW+lvb -> d_out concat
__global__ void k_final(const float* __restrict__ hsum, const float* __restrict__ cnt,
                        const float* __restrict__ muW, const float* __restrict__ mub,
                        const float* __restrict__ lvW, const float* __restrict__ lvb,
                        float* __restrict__ out){
  int i = blockIdx.x*blockDim.x + threadIdx.x;
  if(i >= NG*32*2) return;
  int which = i / (NG*32);
  int r = i % (NG*32);
  int g = r >> 5, j = r & 31;
  float rc = 1.f / fmaxf(cnt[g], 1.f);
  const float* W = which ? lvW : muW;
  float s = which ? lvb[j] : mub[j];
  const float* hr = hsum + (size_t)g*64;
  #pragma unroll 8
  for(int k=0;k<64;k++) s = fmaf(hr[k]*rc, W[k*32+j], s);
  out[i] = s;
}

extern "C" void kernel_launch(void* const* d_in, const int* in_sizes, int n_in,
                              void* d_out, int out_size, void* d_ws, size_t ws_size,
                              hipStream_t stream){
  const float* x      = (const float*)d_in[0];
  const int*   ft     = (const int*)d_in[1];
  const int*   ei     = (const int*)d_in[2];
  const float* eattr  = (const float*)d_in[3];
  const int*   batch  = (const int*)d_in[4];
  const float* mask   = (const float*)d_in[5];
  const float* femb   = (const float*)d_in[7];
  const float* nW     = (const float*)d_in[8];
  const float* nb     = (const float*)d_in[9];
  const float* eW     = (const float*)d_in[10];
  const float* ebias  = (const float*)d_in[11];
  const float* glin   = (const float*)d_in[12];
  const float* gline  = (const float*)d_in[13];
  const float* aS     = (const float*)d_in[14];
  const float* aD     = (const float*)d_in[15];
  const float* aE     = (const float*)d_in[16];
  const float* gbias  = (const float*)d_in[17];
  const float* muW    = (const float*)d_in[18];
  const float* mub    = (const float*)d_in[19];
  const float* lvW    = (const float*)d_in[20];
  const float* lvb    = (const float*)d_in[21];
  const int* src = ei;
  const int* dstp = ei + NE;

  char* ws = (char*)d_ws;
  size_t off = 0;
  auto alloc = [&](size_t bytes)->void*{
    void* p = ws + off; off += (bytes + 255) & ~(size_t)255; return p;
  };
  int*    deg   = (int*)   alloc((size_t)NN*4);
  int*    fill  = (int*)   alloc((size_t)NN*4);
  int*    rp    = (int*)   alloc((size_t)(NN+1)*4);
  int*    bsum  = (int*)   alloc(128*4);
  int*    csrc  = (int*)   alloc((size_t)NE*4);       // 4 MB
  float*  cal   = (float*) alloc((size_t)NL*NE*4*4);  // 48 MB: [l][pos][h]
  float*  alsd  = (float*) alloc((size_t)NN*8*4);
  float*  Ve2   = (float*) alloc((size_t)NL*4*64*4);
  float*  hbuf  = (float*) alloc((size_t)NN*64*4);
  float*  xb    = (float*) alloc((size_t)NN*64*4);
  float*  hsum  = (float*) alloc((size_t)NG*64*4);
  float*  cnt   = (float*) alloc((size_t)NG*4);

  hipMemsetAsync(deg,  0, (size_t)NN*4, stream);
  hipMemsetAsync(fill, 0, (size_t)NN*4, stream);
  hipMemsetAsync(hsum, 0, (size_t)NG*64*4, stream);
  hipMemsetAsync(cnt,  0, (size_t)NG*4, stream);

  k_ve  <<<3, 256, 0, stream>>>(gline, aE, Ve2);
  k_h0  <<<(NN*64+255)/256, 256, 0, stream>>>(x, ft, femb, nW, nb, hbuf);
  k_deg <<<(NE/4+255)/256, 256, 0, stream>>>(dstp, deg);
  k_scan1<<<(NN+1023)/1024, 256, 0, stream>>>(deg, rp, bsum);
  k_scan2<<<1, 64, 0, stream>>>(bsum, (NN+1023)/1024);
  k_scan3<<<(NN+255)/256, 256, 0, stream>>>(rp, bsum);
  k_edge<<<(NE+255)/256, 256, 0, stream>>>(eattr, src, dstp, eW, ebias, Ve2,
                                           rp, fill, csrc, cal);

  for(int l=0;l<NL;l++){
    k_xh <<<(NN+63)/64, 256, 0, stream>>>(hbuf, glin + (size_t)l*4096,
                                          aS + l*64, aD + l*64, xb, alsd);
    k_gat<<<NN/2, 256, 0, stream>>>(xb, alsd, rp, csrc,
                                    cal + (size_t)l*NE*4, gbias + l*64, hbuf);
  }
  k_pool <<<(NN+63)/64, 64, 0, stream>>>(hbuf, batch, mask, hsum, cnt);
  k_final<<<(NG*32*2+255)/256, 256, 0, stream>>>(hsum, cnt, muW, mub, lvW, lvb,
                                                 (float*)d_out);
}

// Round 11
// 510.271 us; speedup vs baseline: 1.0205x; 1.0205x over previous
//
#include <hip/hip_runtime.h>
#include <math.h>

#define NN 100000
#define NE 1000000
#define NG 100
#define NL 3
#define NEG 0.2f

__device__ __forceinline__ float lrelu(float x){ return fmaxf(x, NEG*x); }

// Ve2[(l*4+h)*64 + d] = sum_c We[l][d][h*16+c] * ae[l][h*16+c]  (d-contiguous)
__global__ void k_ve(const float* __restrict__ We, const float* __restrict__ ae,
                     float* __restrict__ Ve2){
  int i = blockIdx.x*blockDim.x + threadIdx.x;
  if(i >= NL*4*64) return;
  int d = i & 63, h = (i>>6)&3, l = i>>8;
  const float* w = We + l*4096 + d*64 + h*16;
  const float* a = ae + l*64 + h*16;
  float s = 0.f;
  #pragma unroll
  for(int c=0;c<16;c++) s = fmaf(w[c], a[c], s);
  Ve2[(l*4+h)*64 + d] = s;
}

// h0 = relu([x, femb[ft]] @ nodeW + b) ; thread per (n,d)
__global__ void k_h0(const float* __restrict__ x, const int* __restrict__ ft,
                     const float* __restrict__ femb, const float* __restrict__ W,
                     const float* __restrict__ b, float* __restrict__ h){
  int i = blockIdx.x*blockDim.x + threadIdx.x;
  if(i >= NN*64) return;
  int n = i>>6, d = i&63;
  const float* xr = x + (size_t)n*9;
  const float* fe = femb + ft[n]*8;
  float s = b[d];
  #pragma unroll
  for(int k=0;k<9;k++) s = fmaf(xr[k], W[k*64+d], s);
  #pragma unroll
  for(int j=0;j<8;j++) s = fmaf(fe[j], W[(9+j)*64+d], s);
  h[i] = fmaxf(s, 0.f);
}

// rank[e] = arrival order among edges sharing dst (atomic return value IS the
// CSR slot index). 4 edges/thread strided -> 4 independent chains in flight.
__global__ void k_deg(const int* __restrict__ dst, int* __restrict__ deg,
                      int* __restrict__ rank){
  int i = blockIdx.x*blockDim.x + threadIdx.x;
  if(i >= NE/4) return;
  #pragma unroll
  for(int k=0;k<4;k++){
    int e = i + k*(NE/4);
    rank[e] = atomicAdd(&deg[dst[e]], 1);
  }
}

// exclusive scan of deg -> rowptr (hierarchical, 1024 elems/block)
__global__ void k_scan1(const int* __restrict__ deg, int* __restrict__ rp,
                        int* __restrict__ bsum){
  __shared__ int sd[256];
  int t = threadIdx.x;
  int base = blockIdx.x*1024 + t*4;
  int v0 = (base+0<NN)?deg[base+0]:0;
  int v1 = (base+1<NN)?deg[base+1]:0;
  int v2 = (base+2<NN)?deg[base+2]:0;
  int v3 = (base+3<NN)?deg[base+3]:0;
  int ts = v0+v1+v2+v3;
  sd[t] = ts; __syncthreads();
  for(int off=1; off<256; off<<=1){
    int add = (t>=off)? sd[t-off] : 0;
    __syncthreads();
    sd[t] += add;
    __syncthreads();
  }
  int excl = sd[t] - ts;
  if(t==255) bsum[blockIdx.x] = sd[t];
  if(base+0<NN) rp[base+0]=excl;
  if(base+1<NN) rp[base+1]=excl+v0;
  if(base+2<NN) rp[base+2]=excl+v0+v1;
  if(base+3<NN) rp[base+3]=excl+v0+v1+v2;
}
__global__ void k_scan2(int* __restrict__ bsum, int nb){
  if(threadIdx.x==0 && blockIdx.x==0){
    int acc=0;
    for(int i=0;i<nb;i++){ int v=bsum[i]; bsum[i]=acc; acc+=v; }
  }
}
__global__ void k_scan3(int* __restrict__ rp, const int* __restrict__ bsum){
  int i = blockIdx.x*blockDim.x + threadIdx.x;
  if(i < NN) rp[i] += bsum[i>>10];
  if(i == 0) rp[NN] = NE;
}

// fused: edge_h = relu(eattr@eW+b); al[l][h] = edge_h . Ve2[l][h][:]
// pos = rp[dst] + rank[e] (NO atomic). One 64B AoS record per CSR slot:
// {src(int), pad3, al[12]} -> exactly one line-write per edge.
__global__ void k_edge(const float* __restrict__ eattr, const int* __restrict__ src,
                       const int* __restrict__ dst, const int* __restrict__ rank,
                       const float* __restrict__ eW, const float* __restrict__ eb,
                       const float* __restrict__ Ve2, const int* __restrict__ rp,
                       float* __restrict__ rec){
  int e = blockIdx.x*blockDim.x + threadIdx.x;
  if(e >= NE) return;
  float a0 = eattr[(size_t)e*2], a1 = eattr[(size_t)e*2+1];
  float acc[12];
  #pragma unroll
  for(int t=0;t<12;t++) acc[t]=0.f;
  #pragma unroll 4
  for(int d=0; d<64; d+=4){
    float4 w0 = *(const float4*)&eW[d];
    float4 w1 = *(const float4*)&eW[64+d];
    float4 bb = *(const float4*)&eb[d];
    float4 eh;
    eh.x = fmaxf(fmaf(a0, w0.x, fmaf(a1, w1.x, bb.x)), 0.f);
    eh.y = fmaxf(fmaf(a0, w0.y, fmaf(a1, w1.y, bb.y)), 0.f);
    eh.z = fmaxf(fmaf(a0, w0.z, fmaf(a1, w1.z, bb.z)), 0.f);
    eh.w = fmaxf(fmaf(a0, w0.w, fmaf(a1, w1.w, bb.w)), 0.f);
    #pragma unroll
    for(int j=0;j<12;j++){
      float4 v = *(const float4*)&Ve2[j*64 + d];
      acc[j] = fmaf(eh.x, v.x, acc[j]);
      acc[j] = fmaf(eh.y, v.y, acc[j]);
      acc[j] = fmaf(eh.z, v.z, acc[j]);
      acc[j] = fmaf(eh.w, v.w, acc[j]);
    }
  }
  int dd = dst[e];
  int pos = rp[dd] + rank[e];
  float* r = rec + (size_t)pos*16;
  *(float4*)(r)    = make_float4(__int_as_float(src[e]), 0.f, 0.f, 0.f);
  *(float4*)(r+4)  = make_float4(acc[0], acc[1], acc[2],  acc[3]);
  *(float4*)(r+8)  = make_float4(acc[4], acc[5], acc[6],  acc[7]);
  *(float4*)(r+12) = make_float4(acc[8], acc[9], acc[10], acc[11]);
}

// xh = h@W as LDS-tiled GEMM: 64-node tile, 256 threads, 4x4 micro-tile/thread.
// Epilogue fuses alsd[n][h] = sum_d xh*aS , sum_d xh*aD via 4-lane shfl reduce.
__global__ __launch_bounds__(256) void k_xh(
    const float* __restrict__ hin, const float* __restrict__ W,
    const float* __restrict__ aS, const float* __restrict__ aD,
    float* __restrict__ xh, float* __restrict__ alsd){
  __shared__ float hs[64][68];
  __shared__ float Ws[64][64];
  int t  = threadIdx.x;
  int td = t & 15;
  int tn = t >> 4;
  int n0 = blockIdx.x*64;
  size_t base = (size_t)n0*64;
  #pragma unroll
  for(int i=0;i<4;i++){
    int idx4 = t + i*256;
    int row  = idx4 >> 4;
    int c4   = (idx4 & 15)*4;
    float4 hv = make_float4(0.f,0.f,0.f,0.f);
    if(base + (size_t)idx4*4 < (size_t)NN*64)
      hv = *(const float4*)&hin[base + (size_t)idx4*4];
    *(float4*)&hs[row][c4] = hv;
    *(float4*)&Ws[row][c4] = *(const float4*)&W[(size_t)idx4*4];
  }
  __syncthreads();

  float acc[4][4];
  #pragma unroll
  for(int i=0;i<4;i++)
    #pragma unroll
    for(int j=0;j<4;j++) acc[i][j]=0.f;

  for(int k=0;k<64;k+=4){
    float4 w0 = *(float4*)&Ws[k+0][td*4];
    float4 w1 = *(float4*)&Ws[k+1][td*4];
    float4 w2 = *(float4*)&Ws[k+2][td*4];
    float4 w3 = *(float4*)&Ws[k+3][td*4];
    #pragma unroll
    for(int i=0;i<4;i++){
      float4 hv = *(float4*)&hs[tn*4+i][k];
      acc[i][0] = fmaf(hv.x, w0.x, acc[i][0]);
      acc[i][1] = fmaf(hv.x, w0.y, acc[i][1]);
      acc[i][2] = fmaf(hv.x, w0.z, acc[i][2]);
      acc[i][3] = fmaf(hv.x, w0.w, acc[i][3]);
      acc[i][0] = fmaf(hv.y, w1.x, acc[i][0]);
      acc[i][1] = fmaf(hv.y, w1.y, acc[i][1]);
      acc[i][2] = fmaf(hv.y, w1.z, acc[i][2]);
      acc[i][3] = fmaf(hv.y, w1.w, acc[i][3]);
      acc[i][0] = fmaf(hv.z, w2.x, acc[i][0]);
      acc[i][1] = fmaf(hv.z, w2.y, acc[i][1]);
      acc[i][2] = fmaf(hv.z, w2.z, acc[i][2]);
      acc[i][3] = fmaf(hv.z, w2.w, acc[i][3]);
      acc[i][0] = fmaf(hv.w, w3.x, acc[i][0]);
      acc[i][1] = fmaf(hv.w, w3.y, acc[i][1]);
      acc[i][2] = fmaf(hv.w, w3.z, acc[i][2]);
      acc[i][3] = fmaf(hv.w, w3.w, acc[i][3]);
    }
  }

  float as0 = aS[td*4+0], as1 = aS[td*4+1], as2 = aS[td*4+2], as3 = aS[td*4+3];
  float ad0 = aD[td*4+0], ad1 = aD[td*4+1], ad2 = aD[td*4+2], ad3 = aD[td*4+3];
  int head = td>>2;

  #pragma unroll
  for(int i=0;i<4;i++){
    int n = n0 + tn*4 + i;
    if(n >= NN) break;
    *(float4*)&xh[(size_t)n*64 + td*4] =
        make_float4(acc[i][0], acc[i][1], acc[i][2], acc[i][3]);
    float vs = acc[i][0]*as0 + acc[i][1]*as1 + acc[i][2]*as2 + acc[i][3]*as3;
    float vd = acc[i][0]*ad0 + acc[i][1]*ad1 + acc[i][2]*ad2 + acc[i][3]*ad3;
    vs += __shfl_xor(vs, 1); vs += __shfl_xor(vs, 2);
    vd += __shfl_xor(vd, 1); vd += __shfl_xor(vd, 2);
    if((td&3)==0){
      alsd[(size_t)n*8 + head]     = vs;
      alsd[(size_t)n*8 + 4 + head] = vd;
    }
  }
}

// per node (1 wave): single pass, defer-max online softmax, 8-edge batches.
// n scalarized (readfirstlane) -> rp/rec-src become s_loads; 16 gathers in
// flight per batch. AoS 64B record: {src, pad3, al[12]}.
__global__ __launch_bounds__(256) void k_gat(
    const float* __restrict__ xh, const float* __restrict__ alsd,
    const int* __restrict__ rp, const float* __restrict__ rec,
    int layer, const float* __restrict__ bias, float* __restrict__ hout){
  int d = threadIdx.x & 63, h = d>>4;
  int n = __builtin_amdgcn_readfirstlane(blockIdx.x*4 + (threadIdx.x>>6));
  if(n >= NN) return;
  int r0 = rp[n], r1 = rp[n+1];          // scalar loads
  int dg = r1 - r0;
  int loff = 4 + layer*4 + h;            // float offset within 16-float record
  float alD_n = alsd[(size_t)n*8 + 4 + h];
  float m = -1e30f, den = 0.f, acc = 0.f, sum_al = 0.f;
  int p = r0;
  for(; p+8 <= r1; p += 8){
    int   s[8]; float e[8]; float a[8]; float x[8];
    #pragma unroll
    for(int k=0;k<8;k++) s[k] = ((const int*)rec)[(size_t)(p+k)*16];  // s_loads
    #pragma unroll
    for(int k=0;k<8;k++) e[k] = rec[(size_t)(p+k)*16 + loff];
    #pragma unroll
    for(int k=0;k<8;k++) a[k] = alsd[(size_t)s[k]*8 + h];
    #pragma unroll
    for(int k=0;k<8;k++) x[k] = xh[(size_t)s[k]*64 + d];
    float lg[8];
    float pmax = -1e30f;
    #pragma unroll
    for(int k=0;k<8;k++){
      sum_al += e[k];
      lg[k] = lrelu(a[k] + alD_n + e[k]);
      pmax = fmaxf(pmax, lg[k]);
    }
    if(pmax > m + 8.f){                  // rare; exp(-1e30-x)->0 handles init
      float sc = __expf(m - pmax);
      den *= sc; acc *= sc; m = pmax;
    }
    #pragma unroll
    for(int k=0;k<8;k++){
      float w = __expf(lg[k] - m);
      den += w;
      acc = fmaf(w, x[k], acc);
    }
  }
  for(; p < r1; p++){
    int s = ((const int*)rec)[(size_t)p*16];
    float e = rec[(size_t)p*16 + loff];
    float as = alsd[(size_t)s*8 + h];
    float xv = xh[(size_t)s*64 + d];
    sum_al += e;
    float lg = lrelu(as + alD_n + e);
    if(lg > m + 8.f){
      float sc = __expf(m - lg);
      den *= sc; acc *= sc; m = lg;
    }
    float w = __expf(lg - m); den += w; acc = fmaf(w, xv, acc);
  }
  // self-loop (exact merge at current reference m)
  float alS_n = alsd[(size_t)n*8 + h];
  float loop_al = dg>0 ? sum_al/(float)dg : 0.f;
  float la = lrelu(alS_n + alD_n + loop_al);
  float nm = fmaxf(m, la);
  float sc = __expf(m - nm);
  float wl = __expf(la - nm);
  den = den*sc + wl;
  acc = fmaf(wl, xh[(size_t)n*64+d], acc*sc);
  hout[(size_t)n*64+d] = fmaxf(acc/den + bias[d], 0.f);
}

// masked scatter-mean pooling: 4 waves/block, each wave owns a 64-node chunk
__global__ __launch_bounds__(256) void k_pool(
    const float* __restrict__ h, const int* __restrict__ batch,
    const float* __restrict__ mask, float* __restrict__ hsum,
    float* __restrict__ cnt){
  int d = threadIdx.x & 63;
  int start = blockIdx.x*256 + (threadIdx.x>>6)*64;
  if(start >= NN) return;
  int end = min(start+64, NN);
  int curg = batch[start];
  float acc = 0.f, c = 0.f;
  for(int n=start; n<end; n++){
    int g = batch[n];
    if(g != curg){
      atomicAdd(&hsum[(size_t)curg*64+d], acc);
      if(d==0) atomicAdd(&cnt[curg], c);
      acc = 0.f; c = 0.f; curg = g;
    }
    float mk = mask[n];
    acc = fmaf(h[(size_t)n*64+d], mk, acc);
    if(d==0) c += mk;
  }
  atomicAdd(&hsum[(size_t)curg*64+d], acc);
  if(d==0) atomicAdd(&cnt[curg], c);
}

// hp = hsum/clip(cnt,1); mu = hp@muW+mub ; logvar = hp@lvW+lvb -> d_out concat
__global__ void k_final(const float* __restrict__ hsum, const float* __restrict__ cnt,
                        const float* __restrict__ muW, const float* __restrict__ mub,
                        const float* __restrict__ lvW, const float* __restrict__ lvb,
                        float* __restrict__ out){
  int i = blockIdx.x*blockDim.x + threadIdx.x;
  if(i >= NG*32*2) return;
  int which = i / (NG*32);
  int r = i % (NG*32);
  int g = r >> 5, j = r & 31;
  float rc = 1.f / fmaxf(cnt[g], 1.f);
  const float* W = which ? lvW : muW;
  float s = which ? lvb[j] : mub[j];
  const float* hr = hsum + (size_t)g*64;
  #pragma unroll 8
  for(int k=0;k<64;k++) s = fmaf(hr[k]*rc, W[k*32+j], s);
  out[i] = s;
}

extern "C" void kernel_launch(void* const* d_in, const int* in_sizes, int n_in,
                              void* d_out, int out_size, void* d_ws, size_t ws_size,
                              hipStream_t stream){
  const float* x      = (const float*)d_in[0];
  const int*   ft     = (const int*)d_in[1];
  const int*   ei     = (const int*)d_in[2];
  const float* eattr  = (const float*)d_in[3];
  const int*   batch  = (const int*)d_in[4];
  const float* mask   = (const float*)d_in[5];
  const float* femb   = (const float*)d_in[7];
  const float* nW     = (const float*)d_in[8];
  const float* nb     = (const float*)d_in[9];
  const float* eW     = (const float*)d_in[10];
  const float* ebias  = (const float*)d_in[11];
  const float* glin   = (const float*)d_in[12];
  const float* gline  = (const float*)d_in[13];
  const float* aS     = (const float*)d_in[14];
  const float* aD     = (const float*)d_in[15];
  const float* aE     = (const float*)d_in[16];
  const float* gbias  = (const float*)d_in[17];
  const float* muW    = (const float*)d_in[18];
  const float* mub    = (const float*)d_in[19];
  const float* lvW    = (const float*)d_in[20];
  const float* lvb    = (const float*)d_in[21];
  const int* src = ei;
  const int* dstp = ei + NE;

  char* ws = (char*)d_ws;
  size_t off = 0;
  auto alloc = [&](size_t bytes)->void*{
    void* p = ws + off; off += (bytes + 255) & ~(size_t)255; return p;
  };
  int*    deg   = (int*)   alloc((size_t)NN*4);
  int*    rank  = (int*)   alloc((size_t)NE*4);       // 4 MB: within-dst rank
  int*    rp    = (int*)   alloc((size_t)(NN+1)*4);
  int*    bsum  = (int*)   alloc(128*4);
  float*  rec   = (float*) alloc((size_t)NE*16*4);    // 64 MB AoS records
  float*  alsd  = (float*) alloc((size_t)NN*8*4);
  float*  Ve2   = (float*) alloc((size_t)NL*4*64*4);
  float*  hbuf  = (float*) alloc((size_t)NN*64*4);
  float*  xb    = (float*) alloc((size_t)NN*64*4);
  float*  hsum  = (float*) alloc((size_t)NG*64*4);
  float*  cnt   = (float*) alloc((size_t)NG*4);

  hipMemsetAsync(deg,  0, (size_t)NN*4, stream);
  hipMemsetAsync(hsum, 0, (size_t)NG*64*4, stream);
  hipMemsetAsync(cnt,  0, (size_t)NG*4, stream);

  k_ve  <<<3, 256, 0, stream>>>(gline, aE, Ve2);
  k_h0  <<<(NN*64+255)/256, 256, 0, stream>>>(x, ft, femb, nW, nb, hbuf);
  k_deg <<<(NE/4+255)/256, 256, 0, stream>>>(dstp, deg, rank);
  k_scan1<<<(NN+1023)/1024, 256, 0, stream>>>(deg, rp, bsum);
  k_scan2<<<1, 64, 0, stream>>>(bsum, (NN+1023)/1024);
  k_scan3<<<(NN+255)/256, 256, 0, stream>>>(rp, bsum);
  k_edge<<<(NE+255)/256, 256, 0, stream>>>(eattr, src, dstp, rank, eW, ebias,
                                           Ve2, rp, rec);

  for(int l=0;l<NL;l++){
    k_xh <<<(NN+63)/64, 256, 0, stream>>>(hbuf, glin + (size_t)l*4096,
                                          aS + l*64, aD + l*64, xb, alsd);
    k_gat<<<(NN+3)/4, 256, 0, stream>>>(xb, alsd, rp, rec, l,
                                        gbias + l*64, hbuf);
  }
  k_pool <<<(NN+255)/256, 256, 0, stream>>>(hbuf, batch, mask, hsum, cnt);
  k_final<<<(NG*32*2+255)/256, 256, 0, stream>>>(hsum, cnt, muW, mub, lvW, lvb,
                                                 (float*)d_out);
}

// Round 12
// 428.907 us; speedup vs baseline: 1.2141x; 1.1897x over previous
//
#include <hip/hip_runtime.h>
#include <math.h>

#define NN 100000
#define NE 1000000
#define NG 100
#define NL 3
#define NEG 0.2f

__device__ __forceinline__ float lrelu(float x){ return fmaxf(x, NEG*x); }

// Ve2[(l*4+h)*64 + d] = sum_c We[l][d][h*16+c] * ae[l][h*16+c]  (d-contiguous)
__global__ void k_ve(const float* __restrict__ We, const float* __restrict__ ae,
                     float* __restrict__ Ve2){
  int i = blockIdx.x*blockDim.x + threadIdx.x;
  if(i >= NL*4*64) return;
  int d = i & 63, h = (i>>6)&3, l = i>>8;
  const float* w = We + l*4096 + d*64 + h*16;
  const float* a = ae + l*64 + h*16;
  float s = 0.f;
  #pragma unroll
  for(int c=0;c<16;c++) s = fmaf(w[c], a[c], s);
  Ve2[(l*4+h)*64 + d] = s;
}

// h0 = relu([x, femb[ft]] @ nodeW + b) ; thread per (n,d)
__global__ void k_h0(const float* __restrict__ x, const int* __restrict__ ft,
                     const float* __restrict__ femb, const float* __restrict__ W,
                     const float* __restrict__ b, float* __restrict__ h){
  int i = blockIdx.x*blockDim.x + threadIdx.x;
  if(i >= NN*64) return;
  int n = i>>6, d = i&63;
  const float* xr = x + (size_t)n*9;
  const float* fe = femb + ft[n]*8;
  float s = b[d];
  #pragma unroll
  for(int k=0;k<9;k++) s = fmaf(xr[k], W[k*64+d], s);
  #pragma unroll
  for(int j=0;j<8;j++) s = fmaf(fe[j], W[(9+j)*64+d], s);
  h[i] = fmaxf(s, 0.f);
}

// rank[e] = atomic return value = CSR slot index within dst's range.
// 4 edges/thread strided -> 4 independent atomic chains in flight.
__global__ void k_deg(const int* __restrict__ dst, int* __restrict__ deg,
                      int* __restrict__ rank){
  int i = blockIdx.x*blockDim.x + threadIdx.x;
  if(i >= NE/4) return;
  #pragma unroll
  for(int k=0;k<4;k++){
    int e = i + k*(NE/4);
    rank[e] = atomicAdd(&deg[dst[e]], 1);
  }
}

// exclusive scan of deg -> rowptr (hierarchical, 1024 elems/block)
__global__ void k_scan1(const int* __restrict__ deg, int* __restrict__ rp,
                        int* __restrict__ bsum){
  __shared__ int sd[256];
  int t = threadIdx.x;
  int base = blockIdx.x*1024 + t*4;
  int v0 = (base+0<NN)?deg[base+0]:0;
  int v1 = (base+1<NN)?deg[base+1]:0;
  int v2 = (base+2<NN)?deg[base+2]:0;
  int v3 = (base+3<NN)?deg[base+3]:0;
  int ts = v0+v1+v2+v3;
  sd[t] = ts; __syncthreads();
  for(int off=1; off<256; off<<=1){
    int add = (t>=off)? sd[t-off] : 0;
    __syncthreads();
    sd[t] += add;
    __syncthreads();
  }
  int excl = sd[t] - ts;
  if(t==255) bsum[blockIdx.x] = sd[t];
  if(base+0<NN) rp[base+0]=excl;
  if(base+1<NN) rp[base+1]=excl+v0;
  if(base+2<NN) rp[base+2]=excl+v0+v1;
  if(base+3<NN) rp[base+3]=excl+v0+v1+v2;
}
__global__ void k_scan2(int* __restrict__ bsum, int nb){
  if(threadIdx.x==0 && blockIdx.x==0){
    int acc=0;
    for(int i=0;i<nb;i++){ int v=bsum[i]; bsum[i]=acc; acc+=v; }
  }
}
__global__ void k_scan3(int* __restrict__ rp, const int* __restrict__ bsum){
  int i = blockIdx.x*blockDim.x + threadIdx.x;
  if(i < NN) rp[i] += bsum[i>>10];
  if(i == 0) rp[NN] = NE;
}

// fused: edge_h = relu(eattr@eW+b); al[l][h] = edge_h . Ve2[l][h][:]
// pos = rp[dst] + rank[e] (NO atomic). Writes: csrc (4B) + split per-layer
// cal streams [l][pos][h] (16B each) -- the k_gat-read-optimal format.
__global__ void k_edge(const float* __restrict__ eattr, const int* __restrict__ src,
                       const int* __restrict__ dst, const int* __restrict__ rank,
                       const float* __restrict__ eW, const float* __restrict__ eb,
                       const float* __restrict__ Ve2, const int* __restrict__ rp,
                       int* __restrict__ csrc, float* __restrict__ cal){
  int e = blockIdx.x*blockDim.x + threadIdx.x;
  if(e >= NE) return;
  float a0 = eattr[(size_t)e*2], a1 = eattr[(size_t)e*2+1];
  float acc[12];
  #pragma unroll
  for(int t=0;t<12;t++) acc[t]=0.f;
  #pragma unroll 4
  for(int d=0; d<64; d+=4){
    float4 w0 = *(const float4*)&eW[d];
    float4 w1 = *(const float4*)&eW[64+d];
    float4 bb = *(const float4*)&eb[d];
    float4 eh;
    eh.x = fmaxf(fmaf(a0, w0.x, fmaf(a1, w1.x, bb.x)), 0.f);
    eh.y = fmaxf(fmaf(a0, w0.y, fmaf(a1, w1.y, bb.y)), 0.f);
    eh.z = fmaxf(fmaf(a0, w0.z, fmaf(a1, w1.z, bb.z)), 0.f);
    eh.w = fmaxf(fmaf(a0, w0.w, fmaf(a1, w1.w, bb.w)), 0.f);
    #pragma unroll
    for(int j=0;j<12;j++){
      float4 v = *(const float4*)&Ve2[j*64 + d];
      acc[j] = fmaf(eh.x, v.x, acc[j]);
      acc[j] = fmaf(eh.y, v.y, acc[j]);
      acc[j] = fmaf(eh.z, v.z, acc[j]);
      acc[j] = fmaf(eh.w, v.w, acc[j]);
    }
  }
  int dd = dst[e];
  int pos = rp[dd] + rank[e];
  csrc[pos] = src[e];
  *(float4*)&cal[(size_t)pos*4]          = make_float4(acc[0], acc[1], acc[2],  acc[3]);
  *(float4*)&cal[((size_t)NE   + pos)*4] = make_float4(acc[4], acc[5], acc[6],  acc[7]);
  *(float4*)&cal[((size_t)NE*2 + pos)*4] = make_float4(acc[8], acc[9], acc[10], acc[11]);
}

// xh = h@W as LDS-tiled GEMM: 64-node tile, 256 threads, 4x4 micro-tile/thread.
// Epilogue fuses alsd[n][h] = sum_d xh*aS , sum_d xh*aD via 4-lane shfl reduce.
__global__ __launch_bounds__(256) void k_xh(
    const float* __restrict__ hin, const float* __restrict__ W,
    const float* __restrict__ aS, const float* __restrict__ aD,
    float* __restrict__ xh, float* __restrict__ alsd){
  __shared__ float hs[64][68];
  __shared__ float Ws[64][64];
  int t  = threadIdx.x;
  int td = t & 15;
  int tn = t >> 4;
  int n0 = blockIdx.x*64;
  size_t base = (size_t)n0*64;
  #pragma unroll
  for(int i=0;i<4;i++){
    int idx4 = t + i*256;
    int row  = idx4 >> 4;
    int c4   = (idx4 & 15)*4;
    float4 hv = make_float4(0.f,0.f,0.f,0.f);
    if(base + (size_t)idx4*4 < (size_t)NN*64)
      hv = *(const float4*)&hin[base + (size_t)idx4*4];
    *(float4*)&hs[row][c4] = hv;
    *(float4*)&Ws[row][c4] = *(const float4*)&W[(size_t)idx4*4];
  }
  __syncthreads();

  float acc[4][4];
  #pragma unroll
  for(int i=0;i<4;i++)
    #pragma unroll
    for(int j=0;j<4;j++) acc[i][j]=0.f;

  for(int k=0;k<64;k+=4){
    float4 w0 = *(float4*)&Ws[k+0][td*4];
    float4 w1 = *(float4*)&Ws[k+1][td*4];
    float4 w2 = *(float4*)&Ws[k+2][td*4];
    float4 w3 = *(float4*)&Ws[k+3][td*4];
    #pragma unroll
    for(int i=0;i<4;i++){
      float4 hv = *(float4*)&hs[tn*4+i][k];
      acc[i][0] = fmaf(hv.x, w0.x, acc[i][0]);
      acc[i][1] = fmaf(hv.x, w0.y, acc[i][1]);
      acc[i][2] = fmaf(hv.x, w0.z, acc[i][2]);
      acc[i][3] = fmaf(hv.x, w0.w, acc[i][3]);
      acc[i][0] = fmaf(hv.y, w1.x, acc[i][0]);
      acc[i][1] = fmaf(hv.y, w1.y, acc[i][1]);
      acc[i][2] = fmaf(hv.y, w1.z, acc[i][2]);
      acc[i][3] = fmaf(hv.y, w1.w, acc[i][3]);
      acc[i][0] = fmaf(hv.z, w2.x, acc[i][0]);
      acc[i][1] = fmaf(hv.z, w2.y, acc[i][1]);
      acc[i][2] = fmaf(hv.z, w2.z, acc[i][2]);
      acc[i][3] = fmaf(hv.z, w2.w, acc[i][3]);
      acc[i][0] = fmaf(hv.w, w3.x, acc[i][0]);
      acc[i][1] = fmaf(hv.w, w3.y, acc[i][1]);
      acc[i][2] = fmaf(hv.w, w3.z, acc[i][2]);
      acc[i][3] = fmaf(hv.w, w3.w, acc[i][3]);
    }
  }

  float as0 = aS[td*4+0], as1 = aS[td*4+1], as2 = aS[td*4+2], as3 = aS[td*4+3];
  float ad0 = aD[td*4+0], ad1 = aD[td*4+1], ad2 = aD[td*4+2], ad3 = aD[td*4+3];
  int head = td>>2;

  #pragma unroll
  for(int i=0;i<4;i++){
    int n = n0 + tn*4 + i;
    if(n >= NN) break;
    *(float4*)&xh[(size_t)n*64 + td*4] =
        make_float4(acc[i][0], acc[i][1], acc[i][2], acc[i][3]);
    float vs = acc[i][0]*as0 + acc[i][1]*as1 + acc[i][2]*as2 + acc[i][3]*as3;
    float vd = acc[i][0]*ad0 + acc[i][1]*ad1 + acc[i][2]*ad2 + acc[i][3]*ad3;
    vs += __shfl_xor(vs, 1); vs += __shfl_xor(vs, 2);
    vd += __shfl_xor(vd, 1); vd += __shfl_xor(vd, 2);
    if((td&3)==0){
      alsd[(size_t)n*8 + head]     = vs;
      alsd[(size_t)n*8 + 4 + head] = vd;
    }
  }
}

// per node (1 wave): single pass, defer-max online softmax, 4-edge batches.
// n scalarized via readfirstlane -> rp/csrc reads become s_loads, loop
// control + cal bases become SALU; per-lane loads are SGPR-base + voff.
__global__ __launch_bounds__(256) void k_gat(
    const float* __restrict__ xh, const float* __restrict__ alsd,
    const int* __restrict__ rp, const int* __restrict__ csrc,
    const float* __restrict__ cal, const float* __restrict__ bias,
    float* __restrict__ hout){
  int d = threadIdx.x & 63, h = d>>4;
  int n = __builtin_amdgcn_readfirstlane(blockIdx.x*4 + (threadIdx.x>>6));
  if(n >= NN) return;
  int r0 = rp[n], r1 = rp[n+1];          // scalar loads
  int dg = r1 - r0;
  float alD_n = alsd[(size_t)n*8 + 4 + h];
  float m = -1e30f, den = 0.f, acc = 0.f, sum_al = 0.f;
  int p = r0;
  for(; p+4 <= r1; p += 4){
    int s0 = csrc[p+0];                  // scalar loads (p scalar)
    int s1 = csrc[p+1];
    int s2 = csrc[p+2];
    int s3 = csrc[p+3];
    float e0 = cal[(size_t)(p+0)*4 + h]; // SGPR base + h*4 voff
    float e1 = cal[(size_t)(p+1)*4 + h];
    float e2 = cal[(size_t)(p+2)*4 + h];
    float e3 = cal[(size_t)(p+3)*4 + h];
    float a0 = alsd[(size_t)s0*8 + h];
    float a1 = alsd[(size_t)s1*8 + h];
    float a2 = alsd[(size_t)s2*8 + h];
    float a3 = alsd[(size_t)s3*8 + h];
    float x0 = xh[(size_t)s0*64 + d];
    float x1 = xh[(size_t)s1*64 + d];
    float x2 = xh[(size_t)s2*64 + d];
    float x3 = xh[(size_t)s3*64 + d];
    sum_al += e0 + e1 + e2 + e3;
    float l0 = lrelu(a0 + alD_n + e0);
    float l1 = lrelu(a1 + alD_n + e1);
    float l2 = lrelu(a2 + alD_n + e2);
    float l3 = lrelu(a3 + alD_n + e3);
    float pmax = fmaxf(fmaxf(l0, l1), fmaxf(l2, l3));
    if(pmax > m + 8.f){                  // rare; exp(-1e30-x)->0 handles init
      float sc = __expf(m - pmax);
      den *= sc; acc *= sc; m = pmax;
    }
    float w0 = __expf(l0 - m); den += w0; acc = fmaf(w0, x0, acc);
    float w1 = __expf(l1 - m); den += w1; acc = fmaf(w1, x1, acc);
    float w2 = __expf(l2 - m); den += w2; acc = fmaf(w2, x2, acc);
    float w3 = __expf(l3 - m); den += w3; acc = fmaf(w3, x3, acc);
  }
  for(; p < r1; p++){
    int s = csrc[p];
    float e = cal[(size_t)p*4 + h];
    float as = alsd[(size_t)s*8 + h];
    float xv = xh[(size_t)s*64 + d];
    sum_al += e;
    float lg = lrelu(as + alD_n + e);
    if(lg > m + 8.f){
      float sc = __expf(m - lg);
      den *= sc; acc *= sc; m = lg;
    }
    float w = __expf(lg - m); den += w; acc = fmaf(w, xv, acc);
  }
  // self-loop (exact merge at current reference m)
  float alS_n = alsd[(size_t)n*8 + h];
  float loop_al = dg>0 ? sum_al/(float)dg : 0.f;
  float la = lrelu(alS_n + alD_n + loop_al);
  float nm = fmaxf(m, la);
  float sc = __expf(m - nm);
  float wl = __expf(la - nm);
  den = den*sc + wl;
  acc = fmaf(wl, xh[(size_t)n*64+d], acc*sc);
  hout[(size_t)n*64+d] = fmaxf(acc/den + bias[d], 0.f);
}

// masked scatter-mean pooling: 4 waves/block, each wave owns a 64-node chunk
__global__ __launch_bounds__(256) void k_pool(
    const float* __restrict__ h, const int* __restrict__ batch,
    const float* __restrict__ mask, float* __restrict__ hsum,
    float* __restrict__ cnt){
  int d = threadIdx.x & 63;
  int start = blockIdx.x*256 + (threadIdx.x>>6)*64;
  if(start >= NN) return;
  int end = min(start+64, NN);
  int curg = batch[start];
  float acc = 0.f, c = 0.f;
  for(int n=start; n<end; n++){
    int g = batch[n];
    if(g != curg){
      atomicAdd(&hsum[(size_t)curg*64+d], acc);
      if(d==0) atomicAdd(&cnt[curg], c);
      acc = 0.f; c = 0.f; curg = g;
    }
    float mk = mask[n];
    acc = fmaf(h[(size_t)n*64+d], mk, acc);
    if(d==0) c += mk;
  }
  atomicAdd(&hsum[(size_t)curg*64+d], acc);
  if(d==0) atomicAdd(&cnt[curg], c);
}

// hp = hsum/clip(cnt,1); mu = hp@muW+mub ; logvar = hp@lvW+lvb -> d_out concat
__global__ void k_final(const float* __restrict__ hsum, const float* __restrict__ cnt,
                        const float* __restrict__ muW, const float* __restrict__ mub,
                        const float* __restrict__ lvW, const float* __restrict__ lvb,
                        float* __restrict__ out){
  int i = blockIdx.x*blockDim.x + threadIdx.x;
  if(i >= NG*32*2) return;
  int which = i / (NG*32);
  int r = i % (NG*32);
  int g = r >> 5, j = r & 31;
  float rc = 1.f / fmaxf(cnt[g], 1.f);
  const float* W = which ? lvW : muW;
  float s = which ? lvb[j] : mub[j];
  const float* hr = hsum + (size_t)g*64;
  #pragma unroll 8
  for(int k=0;k<64;k++) s = fmaf(hr[k]*rc, W[k*32+j], s);
  out[i] = s;
}

extern "C" void kernel_launch(void* const* d_in, const int* in_sizes, int n_in,
                              void* d_out, int out_size, void* d_ws, size_t ws_size,
                              hipStream_t stream){
  const float* x      = (const float*)d_in[0];
  const int*   ft     = (const int*)d_in[1];
  const int*   ei     = (const int*)d_in[2];
  const float* eattr  = (const float*)d_in[3];
  const int*   batch  = (const int*)d_in[4];
  const float* mask   = (const float*)d_in[5];
  const float* femb   = (const float*)d_in[7];
  const float* nW     = (const float*)d_in[8];
  const float* nb     = (const float*)d_in[9];
  const float* eW     = (const float*)d_in[10];
  const float* ebias  = (const float*)d_in[11];
  const float* glin   = (const float*)d_in[12];
  const float* gline  = (const float*)d_in[13];
  const float* aS     = (const float*)d_in[14];
  const float* aD     = (const float*)d_in[15];
  const float* aE     = (const float*)d_in[16];
  const float* gbias  = (const float*)d_in[17];
  const float* muW    = (const float*)d_in[18];
  const float* mub    = (const float*)d_in[19];
  const float* lvW    = (const float*)d_in[20];
  const float* lvb    = (const float*)d_in[21];
  const int* src = ei;
  const int* dstp = ei + NE;

  char* ws = (char*)d_ws;
  size_t off = 0;
  auto alloc = [&](size_t bytes)->void*{
    void* p = ws + off; off += (bytes + 255) & ~(size_t)255; return p;
  };
  int*    deg   = (int*)   alloc((size_t)NN*4);
  int*    rank  = (int*)   alloc((size_t)NE*4);       // 4 MB: within-dst rank
  int*    rp    = (int*)   alloc((size_t)(NN+1)*4);
  int*    bsum  = (int*)   alloc(128*4);
  int*    csrc  = (int*)   alloc((size_t)NE*4);       // 4 MB
  float*  cal   = (float*) alloc((size_t)NL*NE*4*4);  // 48 MB: [l][pos][h]
  float*  alsd  = (float*) alloc((size_t)NN*8*4);
  float*  Ve2   = (float*) alloc((size_t)NL*4*64*4);
  float*  hbuf  = (float*) alloc((size_t)NN*64*4);
  float*  xb    = (float*) alloc((size_t)NN*64*4);
  float*  hsum  = (float*) alloc((size_t)NG*64*4);
  float*  cnt   = (float*) alloc((size_t)NG*4);

  hipMemsetAsync(deg,  0, (size_t)NN*4, stream);
  hipMemsetAsync(hsum, 0, (size_t)NG*64*4, stream);
  hipMemsetAsync(cnt,  0, (size_t)NG*4, stream);

  k_ve  <<<3, 256, 0, stream>>>(gline, aE, Ve2);
  k_h0  <<<(NN*64+255)/256, 256, 0, stream>>>(x, ft, femb, nW, nb, hbuf);
  k_deg <<<(NE/4+255)/256, 256, 0, stream>>>(dstp, deg, rank);
  k_scan1<<<(NN+1023)/1024, 256, 0, stream>>>(deg, rp, bsum);
  k_scan2<<<1, 64, 0, stream>>>(bsum, (NN+1023)/1024);
  k_scan3<<<(NN+255)/256, 256, 0, stream>>>(rp, bsum);
  k_edge<<<(NE+255)/256, 256, 0, stream>>>(eattr, src, dstp, rank, eW, ebias,
                                           Ve2, rp, csrc, cal);

  for(int l=0;l<NL;l++){
    k_xh <<<(NN+63)/64, 256, 0, stream>>>(hbuf, glin + (size_t)l*4096,
                                          aS + l*64, aD + l*64, xb, alsd);
    k_gat<<<(NN+3)/4, 256, 0, stream>>>(xb, alsd, rp, csrc,
                                        cal + (size_t)l*NE*4, gbias + l*64, hbuf);
  }
  k_pool <<<(NN+255)/256, 256, 0, stream>>>(hbuf, batch, mask, hsum, cnt);
  k_final<<<(NG*32*2+255)/256, 256, 0, stream>>>(hsum, cnt, muW, mub, lvW, lvb,
                                                 (float*)d_out);
}